// Round 21
// baseline (722.659 us; speedup 1.0000x reference)
//
#include <hip/hip_runtime.h>
#include <math.h>

typedef __attribute__((ext_vector_type(4))) float f32x4;
typedef __attribute__((ext_vector_type(8))) short bf16x8;
typedef _Float16 f16x8 __attribute__((ext_vector_type(8)));

__device__ __forceinline__ short f2bf(float v) {
    union { float f; unsigned u; } x; x.f = v;
    unsigned r = x.u + 0x7FFF + ((x.u >> 16) & 1);
    return (short)(r >> 16);
}
__device__ __forceinline__ float bf2f(short b) {
    union { unsigned u; float f; } x; x.u = ((unsigned)(unsigned short)b) << 16;
    return x.f;
}
__device__ __forceinline__ short f2h(float v) {
    union { _Float16 h; short s; } u; u.h = (_Float16)v; return u.s;
}
__device__ __forceinline__ void gload16(const void* g, void* l) {
    __builtin_amdgcn_global_load_lds((const __attribute__((address_space(1))) void*)g,
                                     (__attribute__((address_space(3))) void*)l, 16, 0, 0);
}

// ---------------- Stockham radix-2 FFT over ROWS (coalesced) ---------------
// MODE: 0 = real input, 1 = complex input, 2 = mag/pha pair (m*e^{i p})
template<int N, int MODE>
__global__ __launch_bounds__(256)
void fft_lines(const float* __restrict__ in_real, const float* __restrict__ in_pha,
               const float2* __restrict__ in_c, float2* __restrict__ out_c,
               int nlines, int lpp, int plane_stride, int line_pitch, int stride,
               float sgn, float scale)
{
    constexpr int H = N / 2;
    constexpr int LPB = 256 / H;
    __shared__ float2 bufA[LPB][N];
    __shared__ float2 bufB[LPB][N];
    __shared__ float2 W[H];
    const int tid = threadIdx.x;
    const int sub = tid / H;
    const int b   = tid % H;
    const int L   = blockIdx.x * LPB + sub;
    if (tid < H) {
        float ang = (6.283185307179586f / N) * tid;
        float s, c; sincosf(ang, &s, &c);
        W[tid] = make_float2(c, sgn * s);
    }
    const bool active = (L < nlines);
    size_t base = 0;
    if (active) {
        int p = L / lpp, q = L - p * lpp;
        base = (size_t)p * plane_stride + (size_t)q * line_pitch;
        if (MODE == 0) {
            bufA[sub][b]     = make_float2(in_real[base + (size_t)b * stride], 0.f);
            bufA[sub][b + H] = make_float2(in_real[base + (size_t)(b + H) * stride], 0.f);
        } else if (MODE == 1) {
            bufA[sub][b]     = in_c[base + (size_t)b * stride];
            bufA[sub][b + H] = in_c[base + (size_t)(b + H) * stride];
        } else {
            float m0 = in_real[base + (size_t)b * stride];
            float p0 = in_pha [base + (size_t)b * stride];
            float m1 = in_real[base + (size_t)(b + H) * stride];
            float p1 = in_pha [base + (size_t)(b + H) * stride];
            float s0, c0, s1, c1;
            sincosf(p0, &s0, &c0);
            sincosf(p1, &s1, &c1);
            bufA[sub][b]     = make_float2(m0 * c0, m0 * s0);
            bufA[sub][b + H] = make_float2(m1 * c1, m1 * s1);
        }
    }
    __syncthreads();
    float2 (*X)[N] = bufA;
    float2 (*Y)[N] = bufB;
    int m = 1;
    #pragma unroll
    for (int l = H; l >= 1; l >>= 1) {
        int jm = b & ~(m - 1);
        float2 c0 = X[sub][b];
        float2 c1 = X[sub][b + H];
        float2 w  = W[jm];
        float2 s0 = make_float2(c0.x + c1.x, c0.y + c1.y);
        float2 d  = make_float2(c0.x - c1.x, c0.y - c1.y);
        float2 t  = make_float2(d.x * w.x - d.y * w.y, d.x * w.y + d.y * w.x);
        Y[sub][b + jm]     = s0;
        Y[sub][b + jm + m] = t;
        __syncthreads();
        float2 (*tmp)[N] = X; X = Y; Y = tmp;
        m <<= 1;
    }
    if (active) {
        float2 r0 = X[sub][b], r1 = X[sub][b + H];
        out_c[base + (size_t)b * stride]       = make_float2(r0.x * scale, r0.y * scale);
        out_c[base + (size_t)(b + H) * stride] = make_float2(r1.x * scale, r1.y * scale);
    }
}

// ---------------- tiled COLUMN FFT, RADIX-4 Stockham, skewed LDS -----------
template<int N, int TC, int ABSOUT>
__global__ __launch_bounds__(256)
void fft_cols(const float2* __restrict__ in, float2* __restrict__ outc,
              float* __restrict__ outr, float sgn, float scale)
{
    constexpr int Q     = N / 4;
    constexpr int LOG4  = (N == 64) ? 3 : 4;
    constexpr int PITCH = ((N + N / 8 - 8 + 31) / 32) * 32 + 8;
    constexpr int ELD   = (N * TC) / 256;
    constexpr int EBF   = (Q * TC) / 256;
    static_assert((Q * TC) % 256 == 0, "butterfly count must fill block");
    __shared__ float bRe[2][TC * PITCH];
    __shared__ float bIm[2][TC * PITCH];
    __shared__ float Wre[Q + Q / 8 + 1];
    __shared__ float Wim[Q + Q / 8 + 1];
    const int tid = threadIdx.x;
    const int plane = blockIdx.y;
    const int c0 = blockIdx.x * TC;
    const size_t pbase = (size_t)plane * N * N + c0;
    auto lidx = [](int cc, int row) { return cc * PITCH + row + (row >> 3); };

    if (tid < Q) {
        float ang = (6.283185307179586f / N) * tid;
        float s, c; sincosf(ang, &s, &c);
        int wi = tid + (tid >> 3);
        Wre[wi] = c; Wim[wi] = sgn * s;
    }
    #pragma unroll
    for (int e = 0; e < ELD; e++) {
        int q = tid + e * 256;
        int r = q / TC, cc = q % TC;
        float2 v = in[pbase + (size_t)r * N + cc];
        int li = lidx(cc, r);
        bRe[0][li] = v.x; bIm[0][li] = v.y;
    }
    __syncthreads();
    int cur = 0, m = 1;
    #pragma unroll
    for (int stage = 0; stage < LOG4; stage++) {
        #pragma unroll
        for (int e = 0; e < EBF; e++) {
            int idx = tid + e * 256;
            int b = idx % Q, cc = idx / Q;
            int jm = b & ~(m - 1);
            int base = 3 * jm + b;
            int i0 = lidx(cc, b),         i1 = lidx(cc, b + Q);
            int i2 = lidx(cc, b + 2 * Q), i3 = lidx(cc, b + 3 * Q);
            float x0r = bRe[cur][i0], x0i = bIm[cur][i0];
            float x1r = bRe[cur][i1], x1i = bIm[cur][i1];
            float x2r = bRe[cur][i2], x2i = bIm[cur][i2];
            float x3r = bRe[cur][i3], x3i = bIm[cur][i3];
            int wi = jm + (jm >> 3);
            float w1r = Wre[wi], w1i = Wim[wi];
            float w2r = w1r * w1r - w1i * w1i, w2i = 2.f * w1r * w1i;
            float w3r = w2r * w1r - w2i * w1i, w3i = w2r * w1i + w2i * w1r;
            float ar = x0r + x2r, ai = x0i + x2i;
            float br = x0r - x2r, bi = x0i - x2i;
            float cr = x1r + x3r, ci = x1i + x3i;
            float dr = x1r - x3r, di = x1i - x3i;
            float edr = -sgn * di, edi = sgn * dr;
            float y0r = ar + cr,  y0i = ai + ci;
            float y1r = br + edr, y1i = bi + edi;
            float y2r = ar - cr,  y2i = ai - ci;
            float y3r = br - edr, y3i = bi - edi;
            int o0 = lidx(cc, base),         o1 = lidx(cc, base + m);
            int o2 = lidx(cc, base + 2 * m), o3 = lidx(cc, base + 3 * m);
            bRe[cur ^ 1][o0] = y0r;                     bIm[cur ^ 1][o0] = y0i;
            bRe[cur ^ 1][o1] = y1r * w1r - y1i * w1i;   bIm[cur ^ 1][o1] = y1r * w1i + y1i * w1r;
            bRe[cur ^ 1][o2] = y2r * w2r - y2i * w2i;   bIm[cur ^ 1][o2] = y2r * w2i + y2i * w2r;
            bRe[cur ^ 1][o3] = y3r * w3r - y3i * w3i;   bIm[cur ^ 1][o3] = y3r * w3i + y3i * w3r;
        }
        __syncthreads();
        cur ^= 1; m <<= 2;
    }
    #pragma unroll
    for (int e = 0; e < ELD; e++) {
        int q = tid + e * 256;
        int r = q / TC, cc = q % TC;
        int li = lidx(cc, r);
        float vr = bRe[cur][li], vi = bIm[cur][li];
        if (ABSOUT) {
            outr[pbase + (size_t)r * N + cc] = scale * sqrtf(vr * vr + vi * vi);
        } else {
            outc[pbase + (size_t)r * N + cc] = make_float2(vr * scale, vi * scale);
        }
    }
}

// feat extraction, TRANSPOSED: Fc [128 c][4096 o] -> featAbf bf16 [4096][128]
// + featPH f16 [4096][128] (angles)
__global__ __launch_bounds__(256)
void extract_t(const float2* __restrict__ Fc, short* __restrict__ fAbf,
               short* __restrict__ fPH)
{
    __shared__ float2 T[128][17];
    const int tid = threadIdx.x;
    const int o0 = blockIdx.x * 16;
    #pragma unroll
    for (int e = 0; e < 8; e++) {
        int q = tid + e * 256;
        int c = q >> 4, oo = q & 15;
        T[c][oo] = Fc[(size_t)c * 4096 + o0 + oo];
    }
    __syncthreads();
    #pragma unroll
    for (int e = 0; e < 8; e++) {
        int q = tid + e * 256;
        int oo = q >> 7, c = q & 127;
        float2 v = T[c][oo];
        size_t idx = (size_t)(o0 + oo) * 128 + c;
        fAbf[idx] = f2bf(sqrtf(v.x * v.x + v.y * v.y));
        fPH[idx]  = f2h(atan2f(v.y, v.x));
    }
}

// guide extraction, LDS-transposed; Gph f16 [65536][128] (angles)
__global__ __launch_bounds__(256)
void gbuild_t(const float2* __restrict__ E, short* __restrict__ Ga,
              short* __restrict__ Gph)
{
    __shared__ float2 T[128][17];
    const int tid = threadIdx.x;
    const int n0 = blockIdx.x * 16;
    #pragma unroll
    for (int e = 0; e < 8; e++) {
        int q = tid + e * 256;
        int c = q >> 4, nn = q & 15;
        T[c][nn] = E[(size_t)c * 65536 + n0 + nn];
    }
    __syncthreads();
    #pragma unroll
    for (int e = 0; e < 8; e++) {
        int q = tid + e * 256;
        int nn = q >> 7, c = q & 127;
        float2 v = T[c][nn];
        size_t o = (size_t)(n0 + nn) * 128 + c;
        Ga[o]  = f2bf(sqrtf(v.x * v.x + v.y * v.y));
        Gph[o] = f2h(atan2f(v.y, v.x));
    }
}

// per-(shift,n) decode tables: Tcell = cell index or -1; Trel = f16 ry|rx<<16
__global__ __launch_bounds__(256)
void build_tab(int* __restrict__ Tc, unsigned* __restrict__ Tr)
{
    int t = blockIdx.x * 256 + threadIdx.x;   // 4*65536
    int s = t >> 16, nl = t & 65535;
    int oy = (s < 2) ? -3 : 5;
    int ox = (s & 1) ? 5 : -3;
    int i = nl >> 8, jx = nl & 255;
    int iy = (2 * i + oy) >> 3;
    int ix = (2 * jx + ox) >> 3;
    bool valid = (iy >= 0 && iy < 64 && ix >= 0 && ix < 64);
    float ry = valid ? (0.5f * i - 2.f * iy - 0.75f) : (0.5f * i - 63.75f);
    float rx = valid ? (0.5f * jx - 2.f * ix - 0.75f) : (0.5f * jx - 63.75f);
    Tc[t] = valid ? (iy * 64 + ix) : -1;
    Tr[t] = (unsigned)(unsigned short)f2h(ry) | ((unsigned)(unsigned short)f2h(rx) << 16);
}

// mag-path layer-1, factorized, 2 shifts batched: rows n in [0, 131072).
__global__ __launch_bounds__(256)
void mag_h1(const short* __restrict__ FA1, const short* __restrict__ H1g,
            const float* __restrict__ w1a, const float* __restrict__ b1a,
            short* __restrict__ h1, int s0)
{
    int t = blockIdx.x * 256 + threadIdx.x;   // 131072*32
    int n = t >> 5, oc = (t & 31) * 8;
    int im = n >> 16, nl = n & 65535;
    int s = s0 + im;
    int oy = (s < 2) ? -3 : 5;
    int ox = (s & 1) ? 5 : -3;
    int i = nl >> 8, jx = nl & 255;
    int iy = (2 * i + oy) >> 3;
    int ix = (2 * jx + ox) >> 3;
    bool valid = (iy >= 0 && iy < 64 && ix >= 0 && ix < 64);
    float ry = valid ? (0.5f * i - 2.f * iy - 0.75f) : (0.5f * i - 63.75f);
    float rx = valid ? (0.5f * jx - 2.f * ix - 0.75f) : (0.5f * jx - 63.75f);
    bf16x8 hv = *(const bf16x8*)&H1g[(size_t)nl * 256 + oc];
    bf16x8 fv = {};
    if (valid) fv = *(const bf16x8*)&FA1[(size_t)(iy * 64 + ix) * 256 + oc];
    bf16x8 out;
    #pragma unroll
    for (int k = 0; k < 8; k++) {
        int o = oc + k;
        float v = b1a[o] + bf2f(hv[k]) + ry * w1a[128 * 256 + o] + rx * w1a[129 * 256 + o];
        if (valid) v += bf2f(fv[k]);
        out[k] = f2bf(fmaxf(v, 0.f));
    }
    *(bf16x8*)&h1[(size_t)n * 256 + oc] = out;
}

// phase-path input, 2 shifts batched, table-driven decode, f16 gathers.
// Xp2 f16 [2][65536][288]. Grid 4096.
__global__ __launch_bounds__(256)
void bphase_tile(const short* __restrict__ featPH, const short* __restrict__ Gph,
                 const int* __restrict__ Tc, const unsigned* __restrict__ Tr,
                 short* __restrict__ Xp, int s0)
{
    __shared__ short lds[64 * 146];
    const int tid = threadIdx.x;
    const int sh = blockIdx.x >> 11;
    const int inner = blockIdx.x & 2047;
    const int s = s0 + sh;
    const int* Tcs = Tc + s * 65536;
    const unsigned* Trs = Tr + s * 65536;
    const int p0 = (inner >> 1) * 64;
    const int half = inner & 1;
    const int pl = tid & 63;
    const int p = p0 + pl;
    const int jq = tid >> 6;
    unsigned* out32 = (unsigned*)Xp + (size_t)sh * 65536 * 144;
    int j = half * 144 + jq;
    unsigned f0 = (unsigned)j * 65536u + (unsigned)p;
    unsigned n = f0 / 258u;
    int c = (int)(f0 - n * 258u);
    #pragma unroll 4
    for (int e = 0; e < 36; e++) {
        short hv = 0;
        if (j < 258) {
            if (c < 128) {
                int cell = Tcs[n];
                hv = (cell >= 0) ? featPH[(size_t)cell * 128 + c] : (short)0;
            } else if (c < 256) {
                hv = Gph[(size_t)n * 128 + (c - 128)];
            } else {
                unsigned rr = Trs[n];
                hv = (c == 256) ? (short)(rr & 0xffffu) : (short)(rr >> 16);
            }
        }
        lds[pl * 146 + (j - half * 144)] = hv;
        j += 4; n += 1016; c += 16;
        if (c >= 258) { c -= 258; n += 1; }
    }
    __syncthreads();
    const unsigned* lds32 = (const unsigned*)lds;
    int pw = tid / 72, dw = tid - pw * 72;
    #pragma unroll 4
    for (int e = 0; e < 18; e++) {
        out32[(size_t)(p0 + pw) * 144 + half * 72 + dw] = lds32[pw * 73 + dw];
        pw += 3; dw += 40;
        if (dw >= 72) { dw -= 72; pw += 1; }
    }
}

// ---------------- weight prep ----------------
__global__ void wprep_T(const float* __restrict__ src, short* __restrict__ dst,
                        int Ncols, int Nd, int Kp, int k0, int kn, int kr0, int krn)
{
    int t = blockIdx.x * 256 + threadIdx.x;
    if (t >= Nd * Kp) return;
    int o = t / Kp, j = t - o * Kp;
    int c = (j < kn) ? (k0 + j) : ((j < kn + krn) ? (kr0 + j - kn) : -1);
    float v = 0.f;
    if (c >= 0 && o < Ncols) v = src[(size_t)c * Ncols + o];
    dst[t] = f2bf(v);
}
__global__ void wprep_f16(const float* __restrict__ src, short* __restrict__ dst,
                          int Nsrc, int Ksrc, int Nd, int Kp, int kn)
{
    int t = blockIdx.x * 256 + threadIdx.x;
    if (t >= Nd * Kp) return;
    int o = t / Kp, j = t - o * Kp;
    float v = 0.f;
    if (j < kn && o < Nsrc) v = src[(size_t)o * Ksrc + j];
    dst[t] = f2h(v);
}

// ---------------- MFMA GEMM ----------------
template<int RELU, int BIAS, int CIN, int OUTT, int F16>
__global__ __launch_bounds__(256)
void gemm_mfma(const short* __restrict__ A, const short* __restrict__ Bt,
               const float* __restrict__ bias, const void* __restrict__ Cin,
               void* __restrict__ Cout,
               int K, int Apitch, int Bpitch, int ldc, int Nout)
{
    __shared__ short As[4096];
    __shared__ short Bs[4096];
    const int tid = threadIdx.x;
    const int wave = tid >> 6, lane = tid & 63;
    const int bm = blockIdx.y * 128, bn = blockIdx.x * 128;
    const int wr = wave >> 1, wc = wave & 1;
    const int srow = wave * 32 + (lane >> 2);
    const int scol = (lane & 3) * 8;
    const int ldsoff = srow * 32 + scol;
    f32x4 acc[4][4] = {};
    const int ks_n = K >> 5;
    for (int ks = 0; ks < ks_n; ks++) {
        const int k0 = ks << 5;
        const short* gA = A + (size_t)(bm + srow) * Apitch + k0 + scol;
        gload16(gA, &As[ldsoff]);
        gload16(gA + 16 * Apitch, &As[ldsoff + 512]);
        const short* gB = Bt + (size_t)(bn + srow) * Bpitch + k0 + scol;
        gload16(gB, &Bs[ldsoff]);
        gload16(gB + 16 * Bpitch, &Bs[ldsoff + 512]);
        __syncthreads();
        const int fr = lane & 15;
        const int kreg = (lane >> 4) << 3;
        bf16x8 ah[4], bh[4];
        #pragma unroll
        for (int m = 0; m < 4; m++)
            ah[m] = *(const bf16x8*)&As[(wr * 64 + m * 16 + fr) * 32 + kreg];
        #pragma unroll
        for (int n = 0; n < 4; n++)
            bh[n] = *(const bf16x8*)&Bs[(wc * 64 + n * 16 + fr) * 32 + kreg];
        #pragma unroll
        for (int m = 0; m < 4; m++)
            #pragma unroll
            for (int n = 0; n < 4; n++) {
                if constexpr (F16)
                    acc[m][n] = __builtin_amdgcn_mfma_f32_16x16x32_f16(
                        __builtin_bit_cast(f16x8, ah[m]),
                        __builtin_bit_cast(f16x8, bh[n]), acc[m][n], 0, 0, 0);
                else
                    acc[m][n] = __builtin_amdgcn_mfma_f32_16x16x32_bf16(
                        ah[m], bh[n], acc[m][n], 0, 0, 0);
            }
        __syncthreads();
    }
    const int fr = lane & 15;
    const int rg = (lane >> 4) * 4;
    #pragma unroll
    for (int n = 0; n < 4; n++) {
        const int col = bn + wc * 64 + n * 16 + fr;
        if (col >= Nout) continue;
        const float bv = BIAS ? bias[col] : 0.f;
        #pragma unroll
        for (int m = 0; m < 4; m++) {
            const int row0 = bm + wr * 64 + m * 16 + rg;
            #pragma unroll
            for (int r = 0; r < 4; r++) {
                float v = acc[m][n][r] + bv;
                const size_t ci = (size_t)(row0 + r) * ldc + col;
                if (CIN == 1) v += bf2f(((const short*)Cin)[ci]);
                if (RELU) v = fmaxf(v, 0.f);
                if constexpr (OUTT == 1)      ((float*)Cout)[ci] = v;
                else if constexpr (OUTT == 2) ((_Float16*)Cout)[ci] = (_Float16)v;
                else                          ((short*)Cout)[ci] = f2bf(v);
            }
        }
    }
}

// depthwise 3x3, channel-last f16, 2 images batched. 8 ch x 4 px per thread:
// 18 f16x8 (16B) loads issued up-front, packed f16 MAC.
template<int C, int RELU>
__global__ __launch_bounds__(256)
void dwconv_f16(const _Float16* __restrict__ in, const float* __restrict__ w,
                _Float16* __restrict__ out)
{
    constexpr int CG = C / 8;
    constexpr int QPB = 256 / CG;
    constexpr int PX = QPB * 4;
    const int tid = threadIdx.x;
    const int cg = tid % CG;
    const int c8 = cg * 8;
    const int qd = tid / CG;
    const int p0 = blockIdx.x * PX + qd * 4;
    const int im = p0 >> 16;
    const int pl = p0 & 65535;
    const int y = pl >> 8, x0 = pl & 255;
    const size_t ibase = (size_t)im * 65536 * C;
    f16x8 wv[9];
    #pragma unroll
    for (int q = 0; q < 9; q++)
        #pragma unroll
        for (int k = 0; k < 8; k++)
            wv[q][k] = (_Float16)w[(c8 + k) * 9 + q];
    f16x8 v[3][6];
    #pragma unroll
    for (int dy = 0; dy < 3; dy++) {
        int yy = y + dy - 1;
        bool yv = (yy >= 0) && (yy <= 255);
        int yc = min(max(yy, 0), 255);
        #pragma unroll
        for (int dx = 0; dx < 6; dx++) {
            int xx = x0 + dx - 1;
            bool xv = (xx >= 0) && (xx <= 255);
            int xc = min(max(xx, 0), 255);
            f16x8 t = *(const f16x8*)&in[ibase + (size_t)(yc * 256 + xc) * C + c8];
            v[dy][dx] = (yv && xv) ? t : (f16x8){};
        }
    }
    f16x8 acc[4] = {};
    #pragma unroll
    for (int dy = 0; dy < 3; dy++)
        #pragma unroll
        for (int dx = 0; dx < 3; dx++) {
            f16x8 wq = wv[dy * 3 + dx];
            #pragma unroll
            for (int j = 0; j < 4; j++)
                acc[j] += v[dy][j + dx] * wq;
        }
    #pragma unroll
    for (int j = 0; j < 4; j++) {
        if (RELU) {
            #pragma unroll
            for (int k = 0; k < 8; k++)
                acc[j][k] = acc[j][k] > (_Float16)0.f ? acc[j][k] : (_Float16)0.f;
        }
        *(f16x8*)&out[(size_t)(p0 + j) * C + c8] = acc[j];
    }
}

// dw3, 2 images batched: in [2·65536][33] f32 -> out [im][33][65536] f32.
__global__ __launch_bounds__(256)
void dwconv3_t(const float* __restrict__ in, const float* __restrict__ w,
               float* __restrict__ out)
{
    __shared__ float lds[33][65];
    const int tid = threadIdx.x;
    const int im = blockIdx.x >> 10;
    const int inner = blockIdx.x & 1023;
    const int y = inner >> 2;
    const int x0 = (inner & 3) * 64;
    const size_t ibase = (size_t)im * 65536 * 33;
    const size_t obase = (size_t)im * 65536 * 33;
    #pragma unroll
    for (int e = 0; e < 9; e++) {
        int q = e * 256 + tid;
        if (q < 2112) {
            int x = q / 33, c = q - x * 33;
            float acc = 0.f;
            #pragma unroll
            for (int dy = 0; dy < 3; dy++) {
                int yy = y + dy - 1;
                bool yv = (yy >= 0) && (yy <= 255);
                int yc = min(max(yy, 0), 255);
                #pragma unroll
                for (int dx = 0; dx < 3; dx++) {
                    int xx = x0 + x + dx - 1;
                    bool xv = (xx >= 0) && (xx <= 255);
                    int xc = min(max(xx, 0), 255);
                    float t = in[ibase + (size_t)(yc * 256 + xc) * 33 + c];
                    acc += ((yv && xv) ? t : 0.f) * w[c * 9 + dy * 3 + dx];
                }
            }
            lds[c][x] = acc;
        }
    }
    __syncthreads();
    const int xx = tid & 63, c4 = tid >> 6;
    #pragma unroll
    for (int cg = 0; cg < 36; cg += 4) {
        int cc = cg + c4;
        if (cc < 33)
            out[obase + (size_t)cc * 65536 + y * 256 + x0 + xx] = lds[cc][xx];
    }
}

// ---------------- ensembles ----------------
__global__ __launch_bounds__(256)
void ensemble_a(const short* __restrict__ P, float* __restrict__ mag)
{
    int n = blockIdx.x * 256 + threadIdx.x;
    float w[4]; float mx = -1e30f;
    #pragma unroll
    for (int s = 0; s < 4; s++) {
        w[s] = bf2f(P[((size_t)s * 65536 + n) * 33 + 32]);
        mx = fmaxf(mx, w[s]);
    }
    float sum = 0.f;
    #pragma unroll
    for (int s = 0; s < 4; s++) { w[s] = expf(w[s] - mx); sum += w[s]; }
    float inv = 1.f / sum;
    for (int ch = 0; ch < 32; ch++) {
        float a = 0.f;
        #pragma unroll
        for (int s = 0; s < 4; s++)
            a += bf2f(P[((size_t)s * 65536 + n) * 33 + ch]) * w[s];
        mag[(size_t)ch * 65536 + n] = a * inv;
    }
}

__global__ __launch_bounds__(256)
void ensemble_p(const float* __restrict__ P, float* __restrict__ pha)
{
    const size_t SOFF = (size_t)65536 * 33;
    int n = blockIdx.x * 256 + threadIdx.x;
    const size_t base = (size_t)n * 33;
    float w[4]; float mx = -1e30f;
    #pragma unroll
    for (int s = 0; s < 4; s++) {
        w[s] = P[(size_t)s * SOFF + base + 32];
        mx = fmaxf(mx, w[s]);
    }
    float sum = 0.f;
    #pragma unroll
    for (int s = 0; s < 4; s++) { w[s] = expf(w[s] - mx); sum += w[s]; }
    float inv = 1.f / sum;
    for (int jj = 0; jj < 32; jj++) {
        float a = 0.f;
        #pragma unroll
        for (int s = 0; s < 4; s++)
            a += P[(size_t)s * SOFF + base + jj] * w[s];
        pha[(size_t)jj * 65536 + n] = a * inv;
    }
}

extern "C" void kernel_launch(void* const* d_in, const int* in_sizes, int n_in,
                              void* d_out, int out_size, void* d_ws, size_t ws_size,
                              hipStream_t stream)
{
    (void)in_sizes; (void)n_in; (void)out_size; (void)ws_size;
    const float* feat = (const float*)d_in[0];
    const float* hr   = (const float*)d_in[2];
    const float* w1a  = (const float*)d_in[3];
    const float* b1a  = (const float*)d_in[4];
    const float* w2a  = (const float*)d_in[5];
    const float* b2a  = (const float*)d_in[6];
    const float* w3a  = (const float*)d_in[7];
    const float* b3a  = (const float*)d_in[8];
    const float* pw1  = (const float*)d_in[9];
    const float* dw1  = (const float*)d_in[10];
    const float* pw2  = (const float*)d_in[11];
    const float* dw2  = (const float*)d_in[12];
    const float* pw3  = (const float*)d_in[13];
    const float* dw3  = (const float*)d_in[14];

    // Workspace: 229,376,000 B (< 257.4 MB proven).
    char* W = (char*)d_ws;
    const size_t oA = 0;
    const size_t oB = 75497472;
    const size_t oC = oB + 67108864;
    const size_t oD = oC + 33554432;
    const size_t oM = oD + 34603008;
    const size_t oF = oM + 12582912;
    const size_t oN = oF + 786432;

    float2* E     = (float2*)(W + oA);
    short*  h1_2  = (short*) (W + oA);
    short*  Xp2   = (short*) (W + oA);
    _Float16* X2_2 = (_Float16*)(W + oA);
    float*  C3_2  = (float*) (W + oA);
    float*  Hp    = (float*) (W + oA);
    float2* Fc    = (float2*)(W + oB);
    short*  Ga    = (short*) (W + oB);
    short*  h2_2  = (short*) (W + oB);
    short*  H1g   = (short*) (W + oB + 33554432);
    _Float16* C1_2 = (_Float16*)(W + oB);
    _Float16* C2_2 = (_Float16*)(W + oB);
    _Float16* X3_2 = (_Float16*)(W + oB + 33554432);
    float2* Z     = (float2*)(W + oB);
    short*  Gph   = (short*) (W + oC);
    short*  PA    = (short*) (W + oD);
    float*  PP    = (float*) (W + oD);
    short*  featPH = (short*)(W + oM);
    float*  Hm     = (float*)(W + oM + 4194304);
    short* W1g = (short*)(W + oF + 81920);
    short* W2  = (short*)(W + oF + 147456);
    short* W3  = (short*)(W + oF + 212992);
    short* Pf  = (short*)(W + oF + 245760);
    short* P2  = (short*)(W + oF + 393216);
    short* P3  = (short*)(W + oF + 458752);
    short* W1a128 = (short*)(W + oF + 491520);
    short* featAbf = (short*)(W + oN);
    short* FA1     = (short*)(W + oN + 1048576);
    int*      Tcell = (int*)     (W + oN + 3145728);  // [4][65536] 1MB
    unsigned* Trel  = (unsigned*)(W + oN + 4194304);  // [4][65536] 1MB

    const size_t SOFF = (size_t)65536 * 33;

    // ---- weight prep + decode tables ----
    wprep_T<<<128, 256, 0, stream>>>(w1a, W1a128, 256, 256, 128, 0, 128, 0, 0);
    wprep_T<<<128, 256, 0, stream>>>(w1a, W1g, 256, 256, 128, 128, 128, 0, 0);
    wprep_T<<<128, 256, 0, stream>>>(w2a, W2, 128, 128, 256, 0, 256, 0, 0);
    wprep_T<<<64,  256, 0, stream>>>(w3a, W3, 33, 128, 128, 0, 128, 0, 0);
    wprep_f16<<<288, 256, 0, stream>>>(pw1, Pf, 256, 258, 256, 288, 258);
    wprep_f16<<<128, 256, 0, stream>>>(pw2, P2, 128, 256, 128, 256, 256);
    wprep_f16<<<64,  256, 0, stream>>>(pw3, P3, 33, 128, 128, 128, 128);
    build_tab<<<1024, 256, 0, stream>>>(Tcell, Trel);

    // ---- forward FFTs ----
    fft_lines<256, 0><<<16384, 256, 0, stream>>>(hr, nullptr, nullptr, E, 32768, 256, 65536, 256, 1, -1.f, 1.f);
    fft_cols<256, 8, 0><<<dim3(32, 128), 256, 0, stream>>>(E, E, nullptr, -1.f, 1.f);
    fft_lines<64, 0><<<1024, 256, 0, stream>>>(feat, nullptr, nullptr, Fc, 8192, 64, 4096, 64, 1, -1.f, 1.f);
    fft_cols<64, 16, 0><<<dim3(4, 128), 256, 0, stream>>>(Fc, Fc, nullptr, -1.f, 1.f);
    extract_t<<<256, 256, 0, stream>>>(Fc, featAbf, featPH);

    // ---- guide mags/angles (E dead after) ----
    gbuild_t<<<4096, 256, 0, stream>>>(E, Ga, Gph);

    // ---- shift-invariant precomputes ----
    gemm_mfma<0,0,0,0,0><<<dim3(2,512), 256, 0, stream>>>(Ga, W1g, nullptr, nullptr, H1g, 128, 128, 128, 256, 256);
    gemm_mfma<0,0,0,0,0><<<dim3(2,32), 256, 0, stream>>>(featAbf, W1a128, nullptr, nullptr, FA1, 128, 128, 128, 256, 256);

    // ---- magnitude path: 2 shifts per batch ----
    for (int s0 = 0; s0 < 4; s0 += 2) {
        mag_h1<<<16384, 256, 0, stream>>>(FA1, H1g, w1a, b1a, h1_2, s0);
        gemm_mfma<1,1,0,0,0><<<dim3(1,1024), 256, 0, stream>>>(h1_2, W2, b2a, nullptr, h2_2, 256, 256, 256, 128, 128);
        gemm_mfma<0,1,0,0,0><<<dim3(1,1024), 256, 0, stream>>>(h2_2, W3, b3a, nullptr, PA + (size_t)s0 * SOFF, 128, 128, 128, 33, 33);
    }
    ensemble_a<<<256, 256, 0, stream>>>(PA, Hm);

    // ---- phase path: 2 shifts per batch ----
    for (int s0 = 0; s0 < 4; s0 += 2) {
        bphase_tile<<<4096, 256, 0, stream>>>(featPH, Gph, Tcell, Trel, Xp2, s0);
        gemm_mfma<0,0,0,2,1><<<dim3(2,1024), 256, 0, stream>>>(Xp2, Pf, nullptr, nullptr, C1_2, 288, 288, 288, 256, 256);
        dwconv_f16<256,1><<<4096, 256, 0, stream>>>(C1_2, dw1, X2_2);
        gemm_mfma<0,0,0,2,1><<<dim3(1,1024), 256, 0, stream>>>((const short*)X2_2, P2, nullptr, nullptr, C2_2, 256, 256, 256, 128, 128);
        dwconv_f16<128,1><<<2048, 256, 0, stream>>>(C2_2, dw2, X3_2);
        gemm_mfma<0,0,0,1,1><<<dim3(1,1024), 256, 0, stream>>>((const short*)X3_2, P3, nullptr, nullptr, C3_2, 128, 128, 128, 33, 33);
        dwconv3_t<<<2048, 256, 0, stream>>>(C3_2, dw3, PP + (size_t)s0 * SOFF);
    }
    ensemble_p<<<256, 256, 0, stream>>>(PP, Hp);

    // ---- inverse FFT ----
    fft_lines<256, 2><<<4096, 256, 0, stream>>>(Hm, Hp, nullptr, Z, 8192, 256, 65536, 256, 1, 1.f, 1.f / 256.f);
    fft_cols<256, 8, 1><<<dim3(32, 32), 256, 0, stream>>>(Z, nullptr, (float*)d_out, 1.f, 1.f / 256.f);
}

// Round 22
// 703.968 us; speedup vs baseline: 1.0266x; 1.0266x over previous
//
#include <hip/hip_runtime.h>
#include <math.h>

typedef __attribute__((ext_vector_type(4))) float f32x4;
typedef __attribute__((ext_vector_type(8))) short bf16x8;
typedef _Float16 f16x8 __attribute__((ext_vector_type(8)));

__device__ __forceinline__ short f2bf(float v) {
    union { float f; unsigned u; } x; x.f = v;
    unsigned r = x.u + 0x7FFF + ((x.u >> 16) & 1);
    return (short)(r >> 16);
}
__device__ __forceinline__ float bf2f(short b) {
    union { unsigned u; float f; } x; x.u = ((unsigned)(unsigned short)b) << 16;
    return x.f;
}
__device__ __forceinline__ short f2h(float v) {
    union { _Float16 h; short s; } u; u.h = (_Float16)v; return u.s;
}
__device__ __forceinline__ void gload16(const void* g, void* l) {
    __builtin_amdgcn_global_load_lds((const __attribute__((address_space(1))) void*)g,
                                     (__attribute__((address_space(3))) void*)l, 16, 0, 0);
}

// ---------------- Stockham radix-2 FFT over ROWS (coalesced) ---------------
// MODE: 0 = real input, 1 = complex input, 2 = mag/pha pair (m*e^{i p})
template<int N, int MODE>
__global__ __launch_bounds__(256)
void fft_lines(const float* __restrict__ in_real, const float* __restrict__ in_pha,
               const float2* __restrict__ in_c, float2* __restrict__ out_c,
               int nlines, int lpp, int plane_stride, int line_pitch, int stride,
               float sgn, float scale)
{
    constexpr int H = N / 2;
    constexpr int LPB = 256 / H;
    __shared__ float2 bufA[LPB][N];
    __shared__ float2 bufB[LPB][N];
    __shared__ float2 W[H];
    const int tid = threadIdx.x;
    const int sub = tid / H;
    const int b   = tid % H;
    const int L   = blockIdx.x * LPB + sub;
    if (tid < H) {
        float ang = (6.283185307179586f / N) * tid;
        float s, c; sincosf(ang, &s, &c);
        W[tid] = make_float2(c, sgn * s);
    }
    const bool active = (L < nlines);
    size_t base = 0;
    if (active) {
        int p = L / lpp, q = L - p * lpp;
        base = (size_t)p * plane_stride + (size_t)q * line_pitch;
        if (MODE == 0) {
            bufA[sub][b]     = make_float2(in_real[base + (size_t)b * stride], 0.f);
            bufA[sub][b + H] = make_float2(in_real[base + (size_t)(b + H) * stride], 0.f);
        } else if (MODE == 1) {
            bufA[sub][b]     = in_c[base + (size_t)b * stride];
            bufA[sub][b + H] = in_c[base + (size_t)(b + H) * stride];
        } else {
            float m0 = in_real[base + (size_t)b * stride];
            float p0 = in_pha [base + (size_t)b * stride];
            float m1 = in_real[base + (size_t)(b + H) * stride];
            float p1 = in_pha [base + (size_t)(b + H) * stride];
            float s0, c0, s1, c1;
            sincosf(p0, &s0, &c0);
            sincosf(p1, &s1, &c1);
            bufA[sub][b]     = make_float2(m0 * c0, m0 * s0);
            bufA[sub][b + H] = make_float2(m1 * c1, m1 * s1);
        }
    }
    __syncthreads();
    float2 (*X)[N] = bufA;
    float2 (*Y)[N] = bufB;
    int m = 1;
    #pragma unroll
    for (int l = H; l >= 1; l >>= 1) {
        int jm = b & ~(m - 1);
        float2 c0 = X[sub][b];
        float2 c1 = X[sub][b + H];
        float2 w  = W[jm];
        float2 s0 = make_float2(c0.x + c1.x, c0.y + c1.y);
        float2 d  = make_float2(c0.x - c1.x, c0.y - c1.y);
        float2 t  = make_float2(d.x * w.x - d.y * w.y, d.x * w.y + d.y * w.x);
        Y[sub][b + jm]     = s0;
        Y[sub][b + jm + m] = t;
        __syncthreads();
        float2 (*tmp)[N] = X; X = Y; Y = tmp;
        m <<= 1;
    }
    if (active) {
        float2 r0 = X[sub][b], r1 = X[sub][b + H];
        out_c[base + (size_t)b * stride]       = make_float2(r0.x * scale, r0.y * scale);
        out_c[base + (size_t)(b + H) * stride] = make_float2(r1.x * scale, r1.y * scale);
    }
}

// ---------------- tiled COLUMN FFT, RADIX-4 Stockham, skewed LDS -----------
template<int N, int TC, int ABSOUT>
__global__ __launch_bounds__(256)
void fft_cols(const float2* __restrict__ in, float2* __restrict__ outc,
              float* __restrict__ outr, float sgn, float scale)
{
    constexpr int Q     = N / 4;
    constexpr int LOG4  = (N == 64) ? 3 : 4;
    constexpr int PITCH = ((N + N / 8 - 8 + 31) / 32) * 32 + 8;
    constexpr int ELD   = (N * TC) / 256;
    constexpr int EBF   = (Q * TC) / 256;
    static_assert((Q * TC) % 256 == 0, "butterfly count must fill block");
    __shared__ float bRe[2][TC * PITCH];
    __shared__ float bIm[2][TC * PITCH];
    __shared__ float Wre[Q + Q / 8 + 1];
    __shared__ float Wim[Q + Q / 8 + 1];
    const int tid = threadIdx.x;
    const int plane = blockIdx.y;
    const int c0 = blockIdx.x * TC;
    const size_t pbase = (size_t)plane * N * N + c0;
    auto lidx = [](int cc, int row) { return cc * PITCH + row + (row >> 3); };

    if (tid < Q) {
        float ang = (6.283185307179586f / N) * tid;
        float s, c; sincosf(ang, &s, &c);
        int wi = tid + (tid >> 3);
        Wre[wi] = c; Wim[wi] = sgn * s;
    }
    #pragma unroll
    for (int e = 0; e < ELD; e++) {
        int q = tid + e * 256;
        int r = q / TC, cc = q % TC;
        float2 v = in[pbase + (size_t)r * N + cc];
        int li = lidx(cc, r);
        bRe[0][li] = v.x; bIm[0][li] = v.y;
    }
    __syncthreads();
    int cur = 0, m = 1;
    #pragma unroll
    for (int stage = 0; stage < LOG4; stage++) {
        #pragma unroll
        for (int e = 0; e < EBF; e++) {
            int idx = tid + e * 256;
            int b = idx % Q, cc = idx / Q;
            int jm = b & ~(m - 1);
            int base = 3 * jm + b;
            int i0 = lidx(cc, b),         i1 = lidx(cc, b + Q);
            int i2 = lidx(cc, b + 2 * Q), i3 = lidx(cc, b + 3 * Q);
            float x0r = bRe[cur][i0], x0i = bIm[cur][i0];
            float x1r = bRe[cur][i1], x1i = bIm[cur][i1];
            float x2r = bRe[cur][i2], x2i = bIm[cur][i2];
            float x3r = bRe[cur][i3], x3i = bIm[cur][i3];
            int wi = jm + (jm >> 3);
            float w1r = Wre[wi], w1i = Wim[wi];
            float w2r = w1r * w1r - w1i * w1i, w2i = 2.f * w1r * w1i;
            float w3r = w2r * w1r - w2i * w1i, w3i = w2r * w1i + w2i * w1r;
            float ar = x0r + x2r, ai = x0i + x2i;
            float br = x0r - x2r, bi = x0i - x2i;
            float cr = x1r + x3r, ci = x1i + x3i;
            float dr = x1r - x3r, di = x1i - x3i;
            float edr = -sgn * di, edi = sgn * dr;
            float y0r = ar + cr,  y0i = ai + ci;
            float y1r = br + edr, y1i = bi + edi;
            float y2r = ar - cr,  y2i = ai - ci;
            float y3r = br - edr, y3i = bi - edi;
            int o0 = lidx(cc, base),         o1 = lidx(cc, base + m);
            int o2 = lidx(cc, base + 2 * m), o3 = lidx(cc, base + 3 * m);
            bRe[cur ^ 1][o0] = y0r;                     bIm[cur ^ 1][o0] = y0i;
            bRe[cur ^ 1][o1] = y1r * w1r - y1i * w1i;   bIm[cur ^ 1][o1] = y1r * w1i + y1i * w1r;
            bRe[cur ^ 1][o2] = y2r * w2r - y2i * w2i;   bIm[cur ^ 1][o2] = y2r * w2i + y2i * w2r;
            bRe[cur ^ 1][o3] = y3r * w3r - y3i * w3i;   bIm[cur ^ 1][o3] = y3r * w3i + y3i * w3r;
        }
        __syncthreads();
        cur ^= 1; m <<= 2;
    }
    #pragma unroll
    for (int e = 0; e < ELD; e++) {
        int q = tid + e * 256;
        int r = q / TC, cc = q % TC;
        int li = lidx(cc, r);
        float vr = bRe[cur][li], vi = bIm[cur][li];
        if (ABSOUT) {
            outr[pbase + (size_t)r * N + cc] = scale * sqrtf(vr * vr + vi * vi);
        } else {
            outc[pbase + (size_t)r * N + cc] = make_float2(vr * scale, vi * scale);
        }
    }
}

// feat extraction, TRANSPOSED: Fc [128 c][4096 o] -> featAbf bf16 [4096][128]
// + featPH f16 [4096][128] (angles)
__global__ __launch_bounds__(256)
void extract_t(const float2* __restrict__ Fc, short* __restrict__ fAbf,
               short* __restrict__ fPH)
{
    __shared__ float2 T[128][17];
    const int tid = threadIdx.x;
    const int o0 = blockIdx.x * 16;
    #pragma unroll
    for (int e = 0; e < 8; e++) {
        int q = tid + e * 256;
        int c = q >> 4, oo = q & 15;
        T[c][oo] = Fc[(size_t)c * 4096 + o0 + oo];
    }
    __syncthreads();
    #pragma unroll
    for (int e = 0; e < 8; e++) {
        int q = tid + e * 256;
        int oo = q >> 7, c = q & 127;
        float2 v = T[c][oo];
        size_t idx = (size_t)(o0 + oo) * 128 + c;
        fAbf[idx] = f2bf(sqrtf(v.x * v.x + v.y * v.y));
        fPH[idx]  = f2h(atan2f(v.y, v.x));
    }
}

// guide extraction, LDS-transposed; Gph f16 [65536][128] (angles)
__global__ __launch_bounds__(256)
void gbuild_t(const float2* __restrict__ E, short* __restrict__ Ga,
              short* __restrict__ Gph)
{
    __shared__ float2 T[128][17];
    const int tid = threadIdx.x;
    const int n0 = blockIdx.x * 16;
    #pragma unroll
    for (int e = 0; e < 8; e++) {
        int q = tid + e * 256;
        int c = q >> 4, nn = q & 15;
        T[c][nn] = E[(size_t)c * 65536 + n0 + nn];
    }
    __syncthreads();
    #pragma unroll
    for (int e = 0; e < 8; e++) {
        int q = tid + e * 256;
        int nn = q >> 7, c = q & 127;
        float2 v = T[c][nn];
        size_t o = (size_t)(n0 + nn) * 128 + c;
        Ga[o]  = f2bf(sqrtf(v.x * v.x + v.y * v.y));
        Gph[o] = f2h(atan2f(v.y, v.x));
    }
}

// mag-path layer-1, factorized, 2 shifts batched: rows n in [0, 131072).
__global__ __launch_bounds__(256)
void mag_h1(const short* __restrict__ FA1, const short* __restrict__ H1g,
            const float* __restrict__ w1a, const float* __restrict__ b1a,
            short* __restrict__ h1, int s0)
{
    int t = blockIdx.x * 256 + threadIdx.x;   // 131072*32
    int n = t >> 5, oc = (t & 31) * 8;
    int im = n >> 16, nl = n & 65535;
    int s = s0 + im;
    int oy = (s < 2) ? -3 : 5;
    int ox = (s & 1) ? 5 : -3;
    int i = nl >> 8, jx = nl & 255;
    int iy = (2 * i + oy) >> 3;
    int ix = (2 * jx + ox) >> 3;
    bool valid = (iy >= 0 && iy < 64 && ix >= 0 && ix < 64);
    float ry = valid ? (0.5f * i - 2.f * iy - 0.75f) : (0.5f * i - 63.75f);
    float rx = valid ? (0.5f * jx - 2.f * ix - 0.75f) : (0.5f * jx - 63.75f);
    bf16x8 hv = *(const bf16x8*)&H1g[(size_t)nl * 256 + oc];
    bf16x8 fv = {};
    if (valid) fv = *(const bf16x8*)&FA1[(size_t)(iy * 64 + ix) * 256 + oc];
    bf16x8 out;
    #pragma unroll
    for (int k = 0; k < 8; k++) {
        int o = oc + k;
        float v = b1a[o] + bf2f(hv[k]) + ry * w1a[128 * 256 + o] + rx * w1a[129 * 256 + o];
        if (valid) v += bf2f(fv[k]);
        out[k] = f2bf(fmaxf(v, 0.f));
    }
    *(bf16x8*)&h1[(size_t)n * 256 + oc] = out;
}

// phase-path input, 2 shifts batched, incremental (n,c) decode, f16 gathers.
// Xp2 f16 [2][65536][288]. Grid 4096.
__global__ __launch_bounds__(256)
void bphase_tile(const short* __restrict__ featPH, const short* __restrict__ Gph,
                 short* __restrict__ Xp, int s0)
{
    __shared__ short lds[64 * 146];
    const int tid = threadIdx.x;
    const int sh = blockIdx.x >> 11;
    const int inner = blockIdx.x & 2047;
    const int s = s0 + sh;
    const int oy = (s < 2) ? -3 : 5;
    const int ox = (s & 1) ? 5 : -3;
    const int p0 = (inner >> 1) * 64;
    const int half = inner & 1;
    const int pl = tid & 63;
    const int p = p0 + pl;
    const int jq = tid >> 6;
    unsigned* out32 = (unsigned*)Xp + (size_t)sh * 65536 * 144;
    int j = half * 144 + jq;
    unsigned f0 = (unsigned)j * 65536u + (unsigned)p;
    unsigned n = f0 / 258u;
    int c = (int)(f0 - n * 258u);
    #pragma unroll 4
    for (int e = 0; e < 36; e++) {
        short hv = 0;
        if (j < 258) {
            int i = (int)(n >> 8), jx = (int)(n & 255);
            int iy = (2 * i + oy) >> 3;
            int ix = (2 * jx + ox) >> 3;
            bool valid = (iy >= 0 && iy < 64 && ix >= 0 && ix < 64);
            if (c < 128) {
                hv = valid ? featPH[(size_t)(iy * 64 + ix) * 128 + c] : (short)0;
            } else if (c < 256) {
                hv = Gph[(size_t)n * 128 + (c - 128)];
            } else {
                float fv;
                if (c == 256) fv = valid ? (0.5f * i - 2.f * iy - 0.75f) : (0.5f * i - 63.75f);
                else          fv = valid ? (0.5f * jx - 2.f * ix - 0.75f) : (0.5f * jx - 63.75f);
                hv = f2h(fv);
            }
        }
        lds[pl * 146 + (j - half * 144)] = hv;
        j += 4; n += 1016; c += 16;
        if (c >= 258) { c -= 258; n += 1; }
    }
    __syncthreads();
    const unsigned* lds32 = (const unsigned*)lds;
    int pw = tid / 72, dw = tid - pw * 72;
    #pragma unroll 4
    for (int e = 0; e < 18; e++) {
        out32[(size_t)(p0 + pw) * 144 + half * 72 + dw] = lds32[pw * 73 + dw];
        pw += 3; dw += 40;
        if (dw >= 72) { dw -= 72; pw += 1; }
    }
}

// ---------------- weight prep ----------------
__global__ void wprep_T(const float* __restrict__ src, short* __restrict__ dst,
                        int Ncols, int Nd, int Kp, int k0, int kn, int kr0, int krn)
{
    int t = blockIdx.x * 256 + threadIdx.x;
    if (t >= Nd * Kp) return;
    int o = t / Kp, j = t - o * Kp;
    int c = (j < kn) ? (k0 + j) : ((j < kn + krn) ? (kr0 + j - kn) : -1);
    float v = 0.f;
    if (c >= 0 && o < Ncols) v = src[(size_t)c * Ncols + o];
    dst[t] = f2bf(v);
}
__global__ void wprep_f16(const float* __restrict__ src, short* __restrict__ dst,
                          int Nsrc, int Ksrc, int Nd, int Kp, int kn)
{
    int t = blockIdx.x * 256 + threadIdx.x;
    if (t >= Nd * Kp) return;
    int o = t / Kp, j = t - o * Kp;
    float v = 0.f;
    if (j < kn && o < Nsrc) v = src[(size_t)o * Ksrc + j];
    dst[t] = f2h(v);
}

// ---------------- MFMA GEMM ----------------
template<int RELU, int BIAS, int CIN, int OUTT, int F16>
__global__ __launch_bounds__(256)
void gemm_mfma(const short* __restrict__ A, const short* __restrict__ Bt,
               const float* __restrict__ bias, const void* __restrict__ Cin,
               void* __restrict__ Cout,
               int K, int Apitch, int Bpitch, int ldc, int Nout)
{
    __shared__ short As[4096];
    __shared__ short Bs[4096];
    const int tid = threadIdx.x;
    const int wave = tid >> 6, lane = tid & 63;
    const int bm = blockIdx.y * 128, bn = blockIdx.x * 128;
    const int wr = wave >> 1, wc = wave & 1;
    const int srow = wave * 32 + (lane >> 2);
    const int scol = (lane & 3) * 8;
    const int ldsoff = srow * 32 + scol;
    f32x4 acc[4][4] = {};
    const int ks_n = K >> 5;
    for (int ks = 0; ks < ks_n; ks++) {
        const int k0 = ks << 5;
        const short* gA = A + (size_t)(bm + srow) * Apitch + k0 + scol;
        gload16(gA, &As[ldsoff]);
        gload16(gA + 16 * Apitch, &As[ldsoff + 512]);
        const short* gB = Bt + (size_t)(bn + srow) * Bpitch + k0 + scol;
        gload16(gB, &Bs[ldsoff]);
        gload16(gB + 16 * Bpitch, &Bs[ldsoff + 512]);
        __syncthreads();
        const int fr = lane & 15;
        const int kreg = (lane >> 4) << 3;
        bf16x8 ah[4], bh[4];
        #pragma unroll
        for (int m = 0; m < 4; m++)
            ah[m] = *(const bf16x8*)&As[(wr * 64 + m * 16 + fr) * 32 + kreg];
        #pragma unroll
        for (int n = 0; n < 4; n++)
            bh[n] = *(const bf16x8*)&Bs[(wc * 64 + n * 16 + fr) * 32 + kreg];
        #pragma unroll
        for (int m = 0; m < 4; m++)
            #pragma unroll
            for (int n = 0; n < 4; n++) {
                if constexpr (F16)
                    acc[m][n] = __builtin_amdgcn_mfma_f32_16x16x32_f16(
                        __builtin_bit_cast(f16x8, ah[m]),
                        __builtin_bit_cast(f16x8, bh[n]), acc[m][n], 0, 0, 0);
                else
                    acc[m][n] = __builtin_amdgcn_mfma_f32_16x16x32_bf16(
                        ah[m], bh[n], acc[m][n], 0, 0, 0);
            }
        __syncthreads();
    }
    const int fr = lane & 15;
    const int rg = (lane >> 4) * 4;
    #pragma unroll
    for (int n = 0; n < 4; n++) {
        const int col = bn + wc * 64 + n * 16 + fr;
        if (col >= Nout) continue;
        const float bv = BIAS ? bias[col] : 0.f;
        #pragma unroll
        for (int m = 0; m < 4; m++) {
            const int row0 = bm + wr * 64 + m * 16 + rg;
            #pragma unroll
            for (int r = 0; r < 4; r++) {
                float v = acc[m][n][r] + bv;
                const size_t ci = (size_t)(row0 + r) * ldc + col;
                if (CIN == 1) v += bf2f(((const short*)Cin)[ci]);
                if (RELU) v = fmaxf(v, 0.f);
                if constexpr (OUTT == 1)      ((float*)Cout)[ci] = v;
                else if constexpr (OUTT == 2) ((_Float16*)Cout)[ci] = (_Float16)v;
                else                          ((short*)Cout)[ci] = f2bf(v);
            }
        }
    }
}

// depthwise 3x3, channel-last f16, 2 images batched. 8 ch x 4 px per thread:
// 18 f16x8 (16B) loads issued up-front, packed f16 MAC.
template<int C, int RELU>
__global__ __launch_bounds__(256)
void dwconv_f16(const _Float16* __restrict__ in, const float* __restrict__ w,
                _Float16* __restrict__ out)
{
    constexpr int CG = C / 8;
    constexpr int QPB = 256 / CG;
    constexpr int PX = QPB * 4;
    const int tid = threadIdx.x;
    const int cg = tid % CG;
    const int c8 = cg * 8;
    const int qd = tid / CG;
    const int p0 = blockIdx.x * PX + qd * 4;
    const int im = p0 >> 16;
    const int pl = p0 & 65535;
    const int y = pl >> 8, x0 = pl & 255;
    const size_t ibase = (size_t)im * 65536 * C;
    f16x8 wv[9];
    #pragma unroll
    for (int q = 0; q < 9; q++)
        #pragma unroll
        for (int k = 0; k < 8; k++)
            wv[q][k] = (_Float16)w[(c8 + k) * 9 + q];
    f16x8 v[3][6];
    #pragma unroll
    for (int dy = 0; dy < 3; dy++) {
        int yy = y + dy - 1;
        bool yv = (yy >= 0) && (yy <= 255);
        int yc = min(max(yy, 0), 255);
        #pragma unroll
        for (int dx = 0; dx < 6; dx++) {
            int xx = x0 + dx - 1;
            bool xv = (xx >= 0) && (xx <= 255);
            int xc = min(max(xx, 0), 255);
            f16x8 t = *(const f16x8*)&in[ibase + (size_t)(yc * 256 + xc) * C + c8];
            v[dy][dx] = (yv && xv) ? t : (f16x8){};
        }
    }
    f16x8 acc[4] = {};
    #pragma unroll
    for (int dy = 0; dy < 3; dy++)
        #pragma unroll
        for (int dx = 0; dx < 3; dx++) {
            f16x8 wq = wv[dy * 3 + dx];
            #pragma unroll
            for (int j = 0; j < 4; j++)
                acc[j] += v[dy][j + dx] * wq;
        }
    #pragma unroll
    for (int j = 0; j < 4; j++) {
        if (RELU) {
            #pragma unroll
            for (int k = 0; k < 8; k++)
                acc[j][k] = acc[j][k] > (_Float16)0.f ? acc[j][k] : (_Float16)0.f;
        }
        *(f16x8*)&out[(size_t)(p0 + j) * C + c8] = acc[j];
    }
}

// dw3, 2 images batched: in [2·65536][33] f32 -> out [im][33][65536] f32.
__global__ __launch_bounds__(256)
void dwconv3_t(const float* __restrict__ in, const float* __restrict__ w,
               float* __restrict__ out)
{
    __shared__ float lds[33][65];
    const int tid = threadIdx.x;
    const int im = blockIdx.x >> 10;
    const int inner = blockIdx.x & 1023;
    const int y = inner >> 2;
    const int x0 = (inner & 3) * 64;
    const size_t ibase = (size_t)im * 65536 * 33;
    const size_t obase = (size_t)im * 65536 * 33;
    #pragma unroll
    for (int e = 0; e < 9; e++) {
        int q = e * 256 + tid;
        if (q < 2112) {
            int x = q / 33, c = q - x * 33;
            float acc = 0.f;
            #pragma unroll
            for (int dy = 0; dy < 3; dy++) {
                int yy = y + dy - 1;
                bool yv = (yy >= 0) && (yy <= 255);
                int yc = min(max(yy, 0), 255);
                #pragma unroll
                for (int dx = 0; dx < 3; dx++) {
                    int xx = x0 + x + dx - 1;
                    bool xv = (xx >= 0) && (xx <= 255);
                    int xc = min(max(xx, 0), 255);
                    float t = in[ibase + (size_t)(yc * 256 + xc) * 33 + c];
                    acc += ((yv && xv) ? t : 0.f) * w[c * 9 + dy * 3 + dx];
                }
            }
            lds[c][x] = acc;
        }
    }
    __syncthreads();
    const int xx = tid & 63, c4 = tid >> 6;
    #pragma unroll
    for (int cg = 0; cg < 36; cg += 4) {
        int cc = cg + c4;
        if (cc < 33)
            out[obase + (size_t)cc * 65536 + y * 256 + x0 + xx] = lds[cc][xx];
    }
}

// ---------------- ensembles ----------------
__global__ __launch_bounds__(256)
void ensemble_a(const short* __restrict__ P, float* __restrict__ mag)
{
    int n = blockIdx.x * 256 + threadIdx.x;
    float w[4]; float mx = -1e30f;
    #pragma unroll
    for (int s = 0; s < 4; s++) {
        w[s] = bf2f(P[((size_t)s * 65536 + n) * 33 + 32]);
        mx = fmaxf(mx, w[s]);
    }
    float sum = 0.f;
    #pragma unroll
    for (int s = 0; s < 4; s++) { w[s] = expf(w[s] - mx); sum += w[s]; }
    float inv = 1.f / sum;
    for (int ch = 0; ch < 32; ch++) {
        float a = 0.f;
        #pragma unroll
        for (int s = 0; s < 4; s++)
            a += bf2f(P[((size_t)s * 65536 + n) * 33 + ch]) * w[s];
        mag[(size_t)ch * 65536 + n] = a * inv;
    }
}

__global__ __launch_bounds__(256)
void ensemble_p(const float* __restrict__ P, float* __restrict__ pha)
{
    const size_t SOFF = (size_t)65536 * 33;
    int n = blockIdx.x * 256 + threadIdx.x;
    const size_t base = (size_t)n * 33;
    float w[4]; float mx = -1e30f;
    #pragma unroll
    for (int s = 0; s < 4; s++) {
        w[s] = P[(size_t)s * SOFF + base + 32];
        mx = fmaxf(mx, w[s]);
    }
    float sum = 0.f;
    #pragma unroll
    for (int s = 0; s < 4; s++) { w[s] = expf(w[s] - mx); sum += w[s]; }
    float inv = 1.f / sum;
    for (int jj = 0; jj < 32; jj++) {
        float a = 0.f;
        #pragma unroll
        for (int s = 0; s < 4; s++)
            a += P[(size_t)s * SOFF + base + jj] * w[s];
        pha[(size_t)jj * 65536 + n] = a * inv;
    }
}

extern "C" void kernel_launch(void* const* d_in, const int* in_sizes, int n_in,
                              void* d_out, int out_size, void* d_ws, size_t ws_size,
                              hipStream_t stream)
{
    (void)in_sizes; (void)n_in; (void)out_size; (void)ws_size;
    const float* feat = (const float*)d_in[0];
    const float* hr   = (const float*)d_in[2];
    const float* w1a  = (const float*)d_in[3];
    const float* b1a  = (const float*)d_in[4];
    const float* w2a  = (const float*)d_in[5];
    const float* b2a  = (const float*)d_in[6];
    const float* w3a  = (const float*)d_in[7];
    const float* b3a  = (const float*)d_in[8];
    const float* pw1  = (const float*)d_in[9];
    const float* dw1  = (const float*)d_in[10];
    const float* pw2  = (const float*)d_in[11];
    const float* dw2  = (const float*)d_in[12];
    const float* pw3  = (const float*)d_in[13];
    const float* dw3  = (const float*)d_in[14];

    // Workspace: 227,278,848 B (< 257.4 MB proven).
    char* W = (char*)d_ws;
    const size_t oA = 0;
    const size_t oB = 75497472;
    const size_t oC = oB + 67108864;
    const size_t oD = oC + 33554432;
    const size_t oM = oD + 34603008;
    const size_t oF = oM + 12582912;
    const size_t oN = oF + 786432;

    float2* E     = (float2*)(W + oA);
    short*  h1_2  = (short*) (W + oA);
    short*  Xp2   = (short*) (W + oA);
    _Float16* X2_2 = (_Float16*)(W + oA);
    float*  C3_2  = (float*) (W + oA);
    float*  Hp    = (float*) (W + oA);
    float2* Fc    = (float2*)(W + oB);
    short*  Ga    = (short*) (W + oB);
    short*  h2_2  = (short*) (W + oB);
    short*  H1g   = (short*) (W + oB + 33554432);
    _Float16* C1_2 = (_Float16*)(W + oB);
    _Float16* C2_2 = (_Float16*)(W + oB);
    _Float16* X3_2 = (_Float16*)(W + oB + 33554432);
    float2* Z     = (float2*)(W + oB);
    short*  Gph   = (short*) (W + oC);
    short*  PA    = (short*) (W + oD);
    float*  PP    = (float*) (W + oD);
    short*  featPH = (short*)(W + oM);
    float*  Hm     = (float*)(W + oM + 4194304);
    short* W1g = (short*)(W + oF + 81920);
    short* W2  = (short*)(W + oF + 147456);
    short* W3  = (short*)(W + oF + 212992);
    short* Pf  = (short*)(W + oF + 245760);
    short* P2  = (short*)(W + oF + 393216);
    short* P3  = (short*)(W + oF + 458752);
    short* W1a128 = (short*)(W + oF + 491520);
    short* featAbf = (short*)(W + oN);
    short* FA1     = (short*)(W + oN + 1048576);

    const size_t SOFF = (size_t)65536 * 33;

    // ---- weight prep ----
    wprep_T<<<128, 256, 0, stream>>>(w1a, W1a128, 256, 256, 128, 0, 128, 0, 0);
    wprep_T<<<128, 256, 0, stream>>>(w1a, W1g, 256, 256, 128, 128, 128, 0, 0);
    wprep_T<<<128, 256, 0, stream>>>(w2a, W2, 128, 128, 256, 0, 256, 0, 0);
    wprep_T<<<64,  256, 0, stream>>>(w3a, W3, 33, 128, 128, 0, 128, 0, 0);
    wprep_f16<<<288, 256, 0, stream>>>(pw1, Pf, 256, 258, 256, 288, 258);
    wprep_f16<<<128, 256, 0, stream>>>(pw2, P2, 128, 256, 128, 256, 256);
    wprep_f16<<<64,  256, 0, stream>>>(pw3, P3, 33, 128, 128, 128, 128);

    // ---- forward FFTs ----
    fft_lines<256, 0><<<16384, 256, 0, stream>>>(hr, nullptr, nullptr, E, 32768, 256, 65536, 256, 1, -1.f, 1.f);
    fft_cols<256, 8, 0><<<dim3(32, 128), 256, 0, stream>>>(E, E, nullptr, -1.f, 1.f);
    fft_lines<64, 0><<<1024, 256, 0, stream>>>(feat, nullptr, nullptr, Fc, 8192, 64, 4096, 64, 1, -1.f, 1.f);
    fft_cols<64, 16, 0><<<dim3(4, 128), 256, 0, stream>>>(Fc, Fc, nullptr, -1.f, 1.f);
    extract_t<<<256, 256, 0, stream>>>(Fc, featAbf, featPH);

    // ---- guide mags/angles (E dead after) ----
    gbuild_t<<<4096, 256, 0, stream>>>(E, Ga, Gph);

    // ---- shift-invariant precomputes ----
    gemm_mfma<0,0,0,0,0><<<dim3(2,512), 256, 0, stream>>>(Ga, W1g, nullptr, nullptr, H1g, 128, 128, 128, 256, 256);
    gemm_mfma<0,0,0,0,0><<<dim3(2,32), 256, 0, stream>>>(featAbf, W1a128, nullptr, nullptr, FA1, 128, 128, 128, 256, 256);

    // ---- magnitude path: 2 shifts per batch ----
    for (int s0 = 0; s0 < 4; s0 += 2) {
        mag_h1<<<16384, 256, 0, stream>>>(FA1, H1g, w1a, b1a, h1_2, s0);
        gemm_mfma<1,1,0,0,0><<<dim3(1,1024), 256, 0, stream>>>(h1_2, W2, b2a, nullptr, h2_2, 256, 256, 256, 128, 128);
        gemm_mfma<0,1,0,0,0><<<dim3(1,1024), 256, 0, stream>>>(h2_2, W3, b3a, nullptr, PA + (size_t)s0 * SOFF, 128, 128, 128, 33, 33);
    }
    ensemble_a<<<256, 256, 0, stream>>>(PA, Hm);

    // ---- phase path: 2 shifts per batch ----
    for (int s0 = 0; s0 < 4; s0 += 2) {
        bphase_tile<<<4096, 256, 0, stream>>>(featPH, Gph, Xp2, s0);
        gemm_mfma<0,0,0,2,1><<<dim3(2,1024), 256, 0, stream>>>(Xp2, Pf, nullptr, nullptr, C1_2, 288, 288, 288, 256, 256);
        dwconv_f16<256,1><<<4096, 256, 0, stream>>>(C1_2, dw1, X2_2);
        gemm_mfma<0,0,0,2,1><<<dim3(1,1024), 256, 0, stream>>>((const short*)X2_2, P2, nullptr, nullptr, C2_2, 256, 256, 256, 128, 128);
        dwconv_f16<128,1><<<2048, 256, 0, stream>>>(C2_2, dw2, X3_2);
        gemm_mfma<0,0,0,1,1><<<dim3(1,1024), 256, 0, stream>>>((const short*)X3_2, P3, nullptr, nullptr, C3_2, 128, 128, 128, 33, 33);
        dwconv3_t<<<2048, 256, 0, stream>>>(C3_2, dw3, PP + (size_t)s0 * SOFF);
    }
    ensemble_p<<<256, 256, 0, stream>>>(PP, Hp);

    // ---- inverse FFT ----
    fft_lines<256, 2><<<4096, 256, 0, stream>>>(Hm, Hp, nullptr, Z, 8192, 256, 65536, 256, 1, 1.f, 1.f / 256.f);
    fft_cols<256, 8, 1><<<dim3(32, 32), 256, 0, stream>>>(Z, nullptr, (float*)d_out, 1.f, 1.f / 256.f);
}